// Round 7
// baseline (65.116 us; speedup 1.0000x reference)
//
#include <hip/hip_runtime.h>

// Problem constants (match reference)
#define NB 16      // BATCH
#define NC 32      // IN_CH
#define NO 32      // OUT_CH
#define NM 1024    // NODES
#define SEGS 32
#define WLEN 97    // (N-1)*SEGMENTS + 1
#define MTB 64     // m-nodes per block
#define NPH 8      // c-phases
#define CPH 4      // c per phase

// LDS layout (dynamic, 105 KB):
//   [0, 32768)         wbuf0: phase weight buffer (4c x 32seg x 32o x bf16x4)
//   [32768, 65536)     wbuf1: double buffer
//   [65536, 98304)     float4 blds[32][64]  basis (all c)
//   [98304, 107520)    int    soff[64][36]  byte offset within a phase buffer
//   epilogue overlay on wbuf0: float alds[32][66]
#define WBUF_BYTES 32768
#define BLDS_OFF   65536
#define SOFF_OFF   98304
#define SMEM_BYTES 107520

// round-to-nearest-even fp32 -> bf16 (as uint16 in low bits)
__device__ __forceinline__ unsigned f2bf(float f) {
    unsigned u = __float_as_uint(f);
    return (u + 0x7fffu + ((u >> 16) & 1u)) >> 16;
}

// async global->LDS, 16B per lane; LDS dest is wave-uniform base + lane*16
__device__ __forceinline__ void gld_lds16(const void* g, void* l) {
    __builtin_amdgcn_global_load_lds(
        (const __attribute__((address_space(1))) void*)g,
        (__attribute__((address_space(3))) void*)l, 16, 0, 0);
}

// ---------------------------------------------------------------------------
// Repack w[o][c][0..96] -> w4[c][seg][o] = bf16x4{ w[o][c][3seg .. 3seg+3] }
// 32*32*32 * 8B = 256 KB; layout is phase-linear (8 phases x 32 KB memcpy).
// ---------------------------------------------------------------------------
__global__ __launch_bounds__(256) void repack_w_kernel(const float* __restrict__ w,
                                                       uint2* __restrict__ w4) {
    int i = blockIdx.x * blockDim.x + threadIdx.x;   // 0 .. 32767
    if (i >= NC * SEGS * NO) return;
    int o   = i & 31;
    int seg = (i >> 5) & 31;
    int c   = i >> 10;
    const float* p = w + (o * NC + c) * WLEN + 3 * seg;
    unsigned b0 = f2bf(p[0]);
    unsigned b1 = f2bf(p[1]);
    unsigned b2 = f2bf(p[2]);
    unsigned b3 = f2bf(p[3]);
    w4[i] = make_uint2(b0 | (b1 << 16), b2 | (b3 << 16));
}

__device__ __forceinline__ float4 lagrange_basis(float xv, int& id_out) {
    // id = clip(trunc((x+1)/2*32), 0, 31); (x+1)*16 is bit-exact equal.
    float v  = (xv + 1.0f) * 16.0f;
    int   id = (int)v;                 // trunc-toward-zero == astype(int32)
    id = min(max(id, 0), SEGS - 1);
    // x_in = 32*(x - x_min) - 1, x_min = id/16 - 1 (exact)
    const float x_min = (float)id * 0.0625f - 1.0f;
    const float t     = (xv - x_min) * 32.0f - 1.0f;
    // Lagrange basis at Chebyshev points X = {-1, -0.5, 0.5, 1}
    const float d0 = t + 1.0f;
    const float d1 = t + 0.5f;
    const float d2 = t - 0.5f;
    const float d3 = t - 1.0f;
    float4 bb;
    bb.x = d1 * d2 * d3 * (-0.66666667f);  // denom -1.5
    bb.y = d0 * d2 * d3 * ( 1.33333333f);  // denom  0.75
    bb.z = d0 * d1 * d3 * (-1.33333333f);  // denom -0.75
    bb.w = d0 * d1 * d2 * ( 0.66666667f);  // denom  1.5
    id_out = id;
    return bb;
}

// ---------------------------------------------------------------------------
// Main kernel: 256 blocks (1/CU) x 1024 threads (16 waves/CU).
// Block = (b, 64-node tile). 8 c-phases, double-buffered 32KB weight tiles
// staged via global_load_lds (in flight across the whole compute phase).
// Thread = (o-pair = t&15, m = t>>4). Per phase: 1 int4 soff + 4 x
// { b128 basis broadcast, b128 o-pair gather (bank-uniform), 8 expand, 8 FMA }.
// ---------------------------------------------------------------------------
__global__ __launch_bounds__(1024, 4) void pw_main_kernel(const float* __restrict__ x,
                                                          const uint2* __restrict__ w4,
                                                          float* __restrict__ out) {
    extern __shared__ char smem[];
    char* const wbuf0 = smem;
    char* const wbuf1 = smem + WBUF_BYTES;
    float4*     blds  = (float4*)(smem + BLDS_OFF);
    int*        soff  = (int*)(smem + SOFF_OFF);
    float*      alds  = (float*)smem;                 // epilogue overlay

    const int blk = blockIdx.x;          // 0 .. 255
    const int b   = blk >> 4;            // 16 batches
    const int m0  = (blk & 15) * MTB;    // node-tile base

    const int t    = threadIdx.x;
    const int lane = t & 63;
    const int wv   = t >> 6;             // wave 0..15 (wave-uniform)
    const int o2   = t & 15;             // o-pair: o = 2*o2, 2*o2+1
    const int ms   = t >> 4;             // m slot 0..63

    const char* gw = (const char*)w4;

    // ---- issue stage for phase 0 (2 KB per wave: 2 x 1KB dwordx4 sets)
    {
        char* ld = wbuf0 + wv * 2048;
        const char* gs = gw + wv * 2048 + lane * 16;
        gld_lds16(gs, ld);
        gld_lds16(gs + 1024, ld + 1024);
    }

    // ---- basis + soff for all 32 c (overlaps stage-0 flight)
#pragma unroll
    for (int k = 0; k < 2; ++k) {
        const int task = t + 1024 * k;
        const int c = task >> 6;         // k=0: 0..15, k=1: 16..31
        const int m = task & 63;
        const float xv = x[(b * NC + c) * NM + m0 + m];
        int id;
        float4 bb = lagrange_basis(xv, id);
        blds[c * 64 + m] = bb;
        soff[m * 36 + c] = (c & 3) * 8192 + id * 256;   // byte off in phase buf
    }
    __syncthreads();                     // stage 0 drained + basis visible

    float acc0 = 0.0f, acc1 = 0.0f;

#pragma unroll
    for (int ph = 0; ph < NPH; ++ph) {
        const char* wb = (ph & 1) ? wbuf1 : wbuf0;

        // issue next stage into the other buffer (in flight through compute)
        if (ph < NPH - 1) {
            char* ld = ((ph & 1) ? wbuf0 : wbuf1) + wv * 2048;
            const char* gs = gw + (ph + 1) * WBUF_BYTES + wv * 2048 + lane * 16;
            gld_lds16(gs, ld);
            gld_lds16(gs + 1024, ld + 1024);
        }

        // this thread's 4 row offsets (one int4, 16B-aligned)
        const int4 off4 = *(const int4*)&soff[ms * 36 + ph * CPH];

#pragma unroll
        for (int j = 0; j < 4; ++j) {
            const int offb = (j == 0) ? off4.x : (j == 1) ? off4.y
                           : (j == 2) ? off4.z : off4.w;
            const int c = ph * CPH + j;
            const float4 bb = blds[c * 64 + ms];            // 4-addr broadcast
            const uint4  pw = *(const uint4*)(wb + offb + o2 * 16);  // bank-uniform
            acc0 = fmaf(bb.x, __uint_as_float(pw.x << 16), acc0);
            acc0 = fmaf(bb.y, __uint_as_float(pw.x & 0xffff0000u), acc0);
            acc0 = fmaf(bb.z, __uint_as_float(pw.y << 16), acc0);
            acc0 = fmaf(bb.w, __uint_as_float(pw.y & 0xffff0000u), acc0);
            acc1 = fmaf(bb.x, __uint_as_float(pw.z << 16), acc1);
            acc1 = fmaf(bb.y, __uint_as_float(pw.z & 0xffff0000u), acc1);
            acc1 = fmaf(bb.z, __uint_as_float(pw.w << 16), acc1);
            acc1 = fmaf(bb.w, __uint_as_float(pw.w & 0xffff0000u), acc1);
        }
        __syncthreads();   // all reads of wb done; next stage drained (vmcnt0)
    }

    // ---- epilogue: transpose via padded LDS (overlay wbuf0), coalesced write
    alds[(2 * o2) * 66 + ms]     = acc0;      // <=2 lanes/bank: free
    alds[(2 * o2 + 1) * 66 + ms] = acc1;
    __syncthreads();
    {
        const int oo = t >> 5;           // 0..31
        const int mw = t & 31;           // m = 2mw, 2mw+1
        float2 r;
        r.x = alds[oo * 66 + 2 * mw];
        r.y = alds[oo * 66 + 2 * mw + 1];
        *(float2*)&out[(b * NO + oo) * NM + m0 + 2 * mw] = r;
    }
}

// ---------------------------------------------------------------------------
// Fallback (ws too small): one thread per output, direct gather from w.
// ---------------------------------------------------------------------------
__global__ __launch_bounds__(256) void pw_fallback_kernel(const float* __restrict__ x,
                                                          const float* __restrict__ w,
                                                          float* __restrict__ out) {
    const int blk = blockIdx.x;          // 0 .. 2047
    const int b   = blk >> 7;
    const int m   = (blk & 127) * 8 + (threadIdx.x & 7);
    const int o   = threadIdx.x >> 3;

    float acc = 0.0f;
    for (int c = 0; c < NC; ++c) {
        const float xv = x[(b * NC + c) * NM + m];
        int id;
        float4 bb = lagrange_basis(xv, id);
        const float* p = w + (o * NC + c) * WLEN + 3 * id;
        acc = fmaf(bb.x, p[0], acc);
        acc = fmaf(bb.y, p[1], acc);
        acc = fmaf(bb.z, p[2], acc);
        acc = fmaf(bb.w, p[3], acc);
    }
    out[(b * NO + o) * NM + m] = acc;
}

extern "C" void kernel_launch(void* const* d_in, const int* in_sizes, int n_in,
                              void* d_out, int out_size, void* d_ws, size_t ws_size,
                              hipStream_t stream) {
    const float* x = (const float*)d_in[0];   // (16, 32, 1024)
    const float* w = (const float*)d_in[1];   // (32, 32, 97)
    float* out = (float*)d_out;               // (16, 32, 1024)

    const size_t w4_bytes = (size_t)NC * SEGS * NO * sizeof(uint2);  // 256 KB

    hipError_t err = hipFuncSetAttribute((const void*)pw_main_kernel,
                                         hipFuncAttributeMaxDynamicSharedMemorySize,
                                         SMEM_BYTES);

    if (err == hipSuccess && ws_size >= w4_bytes) {
        uint2* w4 = (uint2*)d_ws;
        repack_w_kernel<<<(NC * SEGS * NO + 255) / 256, 256, 0, stream>>>(w, w4);
        pw_main_kernel<<<NB * (NM / MTB), 1024, SMEM_BYTES, stream>>>(x, w4, out);
    } else {
        pw_fallback_kernel<<<NB * (NM / 8), 256, 0, stream>>>(x, w, out);
    }
}